// Round 4
// baseline (289.156 us; speedup 1.0000x reference)
//
#include <hip/hip_runtime.h>
#include <hip/hip_bf16.h>

#define DIN    4096
#define DOUT   11008
#define TM     64
#define KSPLIT 4
#define KCHUNK (DIN / KSPLIT)     // 1024
#define NCHUNKS (DOUT / 16)       // 688

typedef __attribute__((ext_vector_type(8))) short  bf16x8;
typedef __attribute__((ext_vector_type(4))) float  f32x4;

// nontemporal (streaming) 16B load — W is read exactly once; keep it out of L1/L2
__device__ inline f32x4 nt_load4(const float* p) {
    return __builtin_nontemporal_load((const f32x4*)p);
}

// Per-block constants for scaled-domain E2M1 quant-dequant.
// thresholds s2=2*scale, s4=4*scale, s6=6*scale (saturation) and magic
// rounders m05=2^22*scale, m1=2^23*scale, m2=2^24*scale. All exact pow2*scale.
__device__ inline void mx_consts(float amax, float& s2, float& s4, float& s6,
                                 float& m05, float& m1, float& m2) {
    float safe = amax > 0.0f ? amax : 1.0f;
    int e  = (int)((__float_as_uint(safe) >> 23) & 255) - 127;  // floor(log2), normals
    int se = e - 2;
    if (se < -127) se = -127;            // E8M0_MIN clip (matches jnp clip)
    float scale = ldexpf(1.0f, se);
    s2  = scale + scale;
    s4  = s2 + s2;
    s6  = s4 + s2;
    m05 = ldexpf(scale, 22);             // ulp(m05) = scale/2  -> 0.5-step grid
    m1  = m05 + m05;                     // ulp = scale         -> 1-step grid
    m2  = m1 + m1;                       // ulp = 2*scale       -> 2-step grid
}

// E2M1 quant-dequant, scaled domain: clamp to 6*scale, pick step grid by
// magnitude, round-half-even via (a+mg)-mg (== jnp.round semantics), resign.
__device__ inline float mx_qd2(float v, float s2, float s4, float s6,
                               float m05, float m1, float m2) {
    float a  = fminf(fabsf(v), s6);
    float mg = (a < s2) ? m05 : ((a < s4) ? m1 : m2);
    float q  = (a + mg) - mg;            // exact RNE to the grid (no fast-math)
    return copysignf(q, v);
}

__device__ inline short bf16_trunc(float f) {
    // dequantized values have <=2 mantissa bits -> truncation exact
    return (short)(__float_as_uint(f) >> 16);
}

__device__ inline float blk_absmax8(const f32x4& a, const f32x4& b) {
    return fmaxf(fmaxf(fmaxf(fabsf(a[0]), fabsf(a[1])), fmaxf(fabsf(a[2]), fabsf(a[3]))),
                 fmaxf(fmaxf(fabsf(b[0]), fabsf(b[1])), fmaxf(fabsf(b[2]), fabsf(b[3]))));
}

// ---------------- kernel 1: quantize x -> bf16 in ws (exact) ----------------
__global__ __launch_bounds__(256) void quant_x_kernel(const float* __restrict__ x,
                                                      unsigned short* __restrict__ x_dq) {
    int gid = blockIdx.x * 256 + threadIdx.x;       // 65536 threads x 4 elems
    const float4 v = *(const float4*)(x + (size_t)gid * 4);
    float am = fmaxf(fmaxf(fabsf(v.x), fabsf(v.y)), fmaxf(fabsf(v.z), fabsf(v.w)));
    am = fmaxf(am, __shfl_xor(am, 1));
    am = fmaxf(am, __shfl_xor(am, 2));
    am = fmaxf(am, __shfl_xor(am, 4));              // 8-lane group = one 32-block
    float s2, s4, s6, m05, m1, m2;
    mx_consts(am, s2, s4, s6, m05, m1, m2);
    ushort4 q;
    q.x = (unsigned short)bf16_trunc(mx_qd2(v.x, s2, s4, s6, m05, m1, m2));
    q.y = (unsigned short)bf16_trunc(mx_qd2(v.y, s2, s4, s6, m05, m1, m2));
    q.z = (unsigned short)bf16_trunc(mx_qd2(v.z, s2, s4, s6, m05, m1, m2));
    q.w = (unsigned short)bf16_trunc(mx_qd2(v.w, s2, s4, s6, m05, m1, m2));
    *(ushort4*)(x_dq + (size_t)gid * 4) = q;
}

// ---------------- kernel 2: barrier-free fused W-quant GEMM ----------------
// One wave owns 16 N-rows and one K-chunk of 1024. B fragment loaded straight
// from global (n=lane&15, k=quad*8+j -> two float4s; the 4 lanes of one n-row
// cover one contiguous 32-elem MXFP block). 4 MFMAs cover all 64 M rows.
// 2-deep pipeline: W(k+2) in flight | consts(k+1) ready | quant+MFMA(k).
// W loads are nontemporal so the streamed weights don't evict A/x_dq from L1/L2.
__global__ __launch_bounds__(256) void gemm_kernel(const unsigned short* __restrict__ x_dq,
                                                   const float* __restrict__ wgt,
                                                   float* __restrict__ partial) {
    const int lane  = threadIdx.x & 63;
    const int wid   = threadIdx.x >> 6;
    const int w     = blockIdx.x * 4 + wid;         // 0..2751
    const int nch   = w % NCHUNKS;
    const int split = w / NCHUNKS;
    const int nlo   = lane & 15;
    const int kq    = lane >> 4;                    // quad 0..3
    const int kbase = split * KCHUNK + kq * 8;

    const float*          wp = wgt  + (size_t)(nch * 16 + nlo) * DIN + kbase;
    const unsigned short* xp = x_dq + (size_t)nlo * DIN + kbase;

    f32x4 acc0 = {0.f,0.f,0.f,0.f};
    f32x4 acc1 = {0.f,0.f,0.f,0.f};
    f32x4 acc2 = {0.f,0.f,0.f,0.f};
    f32x4 acc3 = {0.f,0.f,0.f,0.f};

    // pipeline prologue: wa = tile0 (consts ready), wb = tile1 arrived/in flight
    f32x4 wa0 = nt_load4(wp);
    f32x4 wa1 = nt_load4(wp + 4);
    f32x4 wb0 = nt_load4(wp + 32);
    f32x4 wb1 = nt_load4(wp + 36);
    float s2, s4, s6, m05, m1, m2;
    {
        float am = blk_absmax8(wa0, wa1);
        am = fmaxf(am, __shfl_xor(am, 16));
        am = fmaxf(am, __shfl_xor(am, 32));
        mx_consts(am, s2, s4, s6, m05, m1, m2);
    }

    // one K-step: quant wa with ready consts, 4 MFMAs, then compute consts for
    // wb (its shfl latency overlaps the MFMAs just issued) and rotate wa<-wb.
    auto step = [&](int kk) {
        bf16x8 a0 = *(const bf16x8*)(xp + kk);
        bf16x8 a1 = *(const bf16x8*)(xp + 16 * DIN + kk);
        bf16x8 a2 = *(const bf16x8*)(xp + 32 * DIN + kk);
        bf16x8 a3 = *(const bf16x8*)(xp + 48 * DIN + kk);

        bf16x8 bf;
        bf[0] = bf16_trunc(mx_qd2(wa0[0], s2, s4, s6, m05, m1, m2));
        bf[1] = bf16_trunc(mx_qd2(wa0[1], s2, s4, s6, m05, m1, m2));
        bf[2] = bf16_trunc(mx_qd2(wa0[2], s2, s4, s6, m05, m1, m2));
        bf[3] = bf16_trunc(mx_qd2(wa0[3], s2, s4, s6, m05, m1, m2));
        bf[4] = bf16_trunc(mx_qd2(wa1[0], s2, s4, s6, m05, m1, m2));
        bf[5] = bf16_trunc(mx_qd2(wa1[1], s2, s4, s6, m05, m1, m2));
        bf[6] = bf16_trunc(mx_qd2(wa1[2], s2, s4, s6, m05, m1, m2));
        bf[7] = bf16_trunc(mx_qd2(wa1[3], s2, s4, s6, m05, m1, m2));

        acc0 = __builtin_amdgcn_mfma_f32_16x16x32_bf16(a0, bf, acc0, 0, 0, 0);
        acc1 = __builtin_amdgcn_mfma_f32_16x16x32_bf16(a1, bf, acc1, 0, 0, 0);
        acc2 = __builtin_amdgcn_mfma_f32_16x16x32_bf16(a2, bf, acc2, 0, 0, 0);
        acc3 = __builtin_amdgcn_mfma_f32_16x16x32_bf16(a3, bf, acc3, 0, 0, 0);

        float amn = blk_absmax8(wb0, wb1);
        amn = fmaxf(amn, __shfl_xor(amn, 16));
        amn = fmaxf(amn, __shfl_xor(amn, 32));
        mx_consts(amn, s2, s4, s6, m05, m1, m2);

        wa0 = wb0; wa1 = wb1;
    };

    #pragma unroll 2
    for (int kk = 0; kk < KCHUNK - 64; kk += 32) {  // 30 iters, prefetch in-bounds
        f32x4 wc0 = nt_load4(wp + kk + 64);
        f32x4 wc1 = nt_load4(wp + kk + 68);
        step(kk);
        wb0 = wc0; wb1 = wc1;
    }
    step(KCHUNK - 64);   // tile 30 (consts flow from wb = tile 31)
    step(KCHUNK - 32);   // tile 31 (trailing consts recompute is dead code)

    // C/D map: col(n)=lane&15, row(m)=quad*4+reg (verified: absmax 0)
    float* pp = partial + (size_t)split * (TM * DOUT) + (size_t)(nch * 16 + nlo);
    const int mrow = kq * 4;
    #pragma unroll
    for (int r = 0; r < 4; ++r) {
        pp[(size_t)(mrow + r) * DOUT]      = acc0[r];
        pp[(size_t)(16 + mrow + r) * DOUT] = acc1[r];
        pp[(size_t)(32 + mrow + r) * DOUT] = acc2[r];
        pp[(size_t)(48 + mrow + r) * DOUT] = acc3[r];
    }
}

// ---------------- kernel 3: reduce K-splits + quantized bias ----------------
__global__ __launch_bounds__(256) void reduce_bias_kernel(const float* __restrict__ partial,
                                                          const float* __restrict__ bias,
                                                          float* __restrict__ out) {
    int gid = blockIdx.x * 256 + threadIdx.x;       // 704512 threads
    float s = 0.f;
    #pragma unroll
    for (int i = 0; i < KSPLIT; ++i)
        s += partial[(size_t)i * (TM * DOUT) + gid];
    int n = gid % DOUT;
    float v = bias[n];
    float am = fabsf(v);
    am = fmaxf(am, __shfl_xor(am, 1));
    am = fmaxf(am, __shfl_xor(am, 2));
    am = fmaxf(am, __shfl_xor(am, 4));
    am = fmaxf(am, __shfl_xor(am, 8));
    am = fmaxf(am, __shfl_xor(am, 16));
    float s2, s4, s6, m05, m1, m2;
    mx_consts(am, s2, s4, s6, m05, m1, m2);
    out[gid] = s + mx_qd2(v, s2, s4, s6, m05, m1, m2);
}

extern "C" void kernel_launch(void* const* d_in, const int* in_sizes, int n_in,
                              void* d_out, int out_size, void* d_ws, size_t ws_size,
                              hipStream_t stream) {
    const float* x    = (const float*)d_in[0];   // [64, 4096]
    const float* wgt  = (const float*)d_in[1];   // [11008, 4096]
    const float* bias = (const float*)d_in[2];   // [11008]
    float* out = (float*)d_out;                  // [64, 11008]

    unsigned short* x_dq    = (unsigned short*)d_ws;                 // 512 KB
    float*          partial = (float*)((char*)d_ws + 512 * 1024);    // 11.25 MB

    quant_x_kernel<<<256, 256, 0, stream>>>(x, x_dq);
    gemm_kernel<<<NCHUNKS * KSPLIT / 4, 256, 0, stream>>>(x_dq, wgt, partial);
    reduce_bias_kernel<<<TM * DOUT / 256, 256, 0, stream>>>(partial, bias, out);
}

// Round 5
// 288.961 us; speedup vs baseline: 1.0007x; 1.0007x over previous
//
#include <hip/hip_runtime.h>
#include <hip/hip_bf16.h>

#define DIN    4096
#define DOUT   11008
#define TM     64
#define KSPLIT 4
#define KCHUNK (DIN / KSPLIT)     // 1024
#define NCHUNKS (DOUT / 16)       // 688

typedef __attribute__((ext_vector_type(8))) short  bf16x8;
typedef __attribute__((ext_vector_type(4))) float  f32x4;

// Per-block constants for scaled-domain E2M1 quant-dequant.
// thresholds s2=2*scale, s4=4*scale, s6=6*scale (saturation) and magic
// rounders m05=2^22*scale, m1=2^23*scale, m2=2^24*scale. All exact pow2*scale.
__device__ inline void mx_consts(float amax, float& s2, float& s4, float& s6,
                                 float& m05, float& m1, float& m2) {
    float safe = amax > 0.0f ? amax : 1.0f;
    int e  = (int)((__float_as_uint(safe) >> 23) & 255) - 127;  // floor(log2), normals
    int se = e - 2;
    if (se < -127) se = -127;            // E8M0_MIN clip (matches jnp clip)
    float scale = ldexpf(1.0f, se);
    s2  = scale + scale;
    s4  = s2 + s2;
    s6  = s4 + s2;
    m05 = ldexpf(scale, 22);             // ulp(m05) = scale/2  -> 0.5-step grid
    m1  = m05 + m05;                     // ulp = scale         -> 1-step grid
    m2  = m1 + m1;                       // ulp = 2*scale       -> 2-step grid
}

// E2M1 quant-dequant, scaled domain: clamp to 6*scale, pick step grid by
// magnitude, round-half-even via (a+mg)-mg (== jnp.round semantics), resign.
__device__ inline float mx_qd2(float v, float s2, float s4, float s6,
                               float m05, float m1, float m2) {
    float a  = fminf(fabsf(v), s6);
    float mg = (a < s2) ? m05 : ((a < s4) ? m1 : m2);
    float q  = (a + mg) - mg;            // exact RNE to the grid (no fast-math)
    return copysignf(q, v);
}

__device__ inline short bf16_trunc(float f) {
    // dequantized values have <=2 mantissa bits -> truncation exact
    return (short)(__float_as_uint(f) >> 16);
}

__device__ inline float blk_absmax8(const f32x4& a, const f32x4& b) {
    return fmaxf(fmaxf(fmaxf(fabsf(a[0]), fabsf(a[1])), fmaxf(fabsf(a[2]), fabsf(a[3]))),
                 fmaxf(fmaxf(fabsf(b[0]), fabsf(b[1])), fmaxf(fabsf(b[2]), fabsf(b[3]))));
}

// ---------------- kernel 1: quantize x -> bf16 in ws (exact) ----------------
__global__ __launch_bounds__(256) void quant_x_kernel(const float* __restrict__ x,
                                                      unsigned short* __restrict__ x_dq) {
    int gid = blockIdx.x * 256 + threadIdx.x;       // 65536 threads x 4 elems
    const float4 v = *(const float4*)(x + (size_t)gid * 4);
    float am = fmaxf(fmaxf(fabsf(v.x), fabsf(v.y)), fmaxf(fabsf(v.z), fabsf(v.w)));
    am = fmaxf(am, __shfl_xor(am, 1));
    am = fmaxf(am, __shfl_xor(am, 2));
    am = fmaxf(am, __shfl_xor(am, 4));              // 8-lane group = one 32-block
    float s2, s4, s6, m05, m1, m2;
    mx_consts(am, s2, s4, s6, m05, m1, m2);
    ushort4 q;
    q.x = (unsigned short)bf16_trunc(mx_qd2(v.x, s2, s4, s6, m05, m1, m2));
    q.y = (unsigned short)bf16_trunc(mx_qd2(v.y, s2, s4, s6, m05, m1, m2));
    q.z = (unsigned short)bf16_trunc(mx_qd2(v.z, s2, s4, s6, m05, m1, m2));
    q.w = (unsigned short)bf16_trunc(mx_qd2(v.w, s2, s4, s6, m05, m1, m2));
    *(ushort4*)(x_dq + (size_t)gid * 4) = q;
}

// ---------------- kernel 2: barrier-free fused W-quant GEMM ----------------
// One wave owns 16 N-rows and one K-chunk of 1024. B fragment loaded straight
// from global (n=lane&15, k=quad*8+j -> two float4s; the 4 lanes of one n-row
// cover one contiguous 32-elem MXFP block). 4 MFMAs cover all 64 M rows.
// Pipeline: W at depth 2 (HBM/L3 latency), A at depth 1 (L2-hit latency),
// consts at depth 1 (shfl latency overlaps the MFMAs just issued).
// Plain (cached) W loads: harness restores W right before launch -> L3-hot.
__global__ __launch_bounds__(256) void gemm_kernel(const unsigned short* __restrict__ x_dq,
                                                   const float* __restrict__ wgt,
                                                   float* __restrict__ partial) {
    const int lane  = threadIdx.x & 63;
    const int wid   = threadIdx.x >> 6;
    const int w     = blockIdx.x * 4 + wid;         // 0..2751
    const int nch   = w % NCHUNKS;
    const int split = w / NCHUNKS;
    const int nlo   = lane & 15;
    const int kq    = lane >> 4;                    // quad 0..3
    const int kbase = split * KCHUNK + kq * 8;

    const float*          wp = wgt  + (size_t)(nch * 16 + nlo) * DIN + kbase;
    const unsigned short* xp = x_dq + (size_t)nlo * DIN + kbase;

    f32x4 acc0 = {0.f,0.f,0.f,0.f};
    f32x4 acc1 = {0.f,0.f,0.f,0.f};
    f32x4 acc2 = {0.f,0.f,0.f,0.f};
    f32x4 acc3 = {0.f,0.f,0.f,0.f};

    // prologue: W tiles 0 (consts ready) and 1 in flight; A frags for tile 0
    f32x4 wa0 = *(const f32x4*)(wp);
    f32x4 wa1 = *(const f32x4*)(wp + 4);
    f32x4 wb0 = *(const f32x4*)(wp + 32);
    f32x4 wb1 = *(const f32x4*)(wp + 36);
    bf16x8 aa0 = *(const bf16x8*)(xp);
    bf16x8 aa1 = *(const bf16x8*)(xp + 16 * DIN);
    bf16x8 aa2 = *(const bf16x8*)(xp + 32 * DIN);
    bf16x8 aa3 = *(const bf16x8*)(xp + 48 * DIN);
    float s2, s4, s6, m05, m1, m2;
    {
        float am = blk_absmax8(wa0, wa1);
        am = fmaxf(am, __shfl_xor(am, 16));
        am = fmaxf(am, __shfl_xor(am, 32));
        mx_consts(am, s2, s4, s6, m05, m1, m2);
    }

    #pragma unroll 2
    for (int kk = 0; kk < KCHUNK; kk += 32) {
        // prefetch W(k+2) and A(k+1); clamp keeps the tail in-bounds (dup load)
        const int kw = (kk + 64 < KCHUNK) ? kk + 64 : KCHUNK - 32;
        const int ka = (kk + 32 < KCHUNK) ? kk + 32 : KCHUNK - 32;
        f32x4 wc0 = *(const f32x4*)(wp + kw);
        f32x4 wc1 = *(const f32x4*)(wp + kw + 4);
        bf16x8 ab0 = *(const bf16x8*)(xp + ka);
        bf16x8 ab1 = *(const bf16x8*)(xp + 16 * DIN + ka);
        bf16x8 ab2 = *(const bf16x8*)(xp + 32 * DIN + ka);
        bf16x8 ab3 = *(const bf16x8*)(xp + 48 * DIN + ka);

        // quantize current W tile with the pre-computed consts
        bf16x8 bf;
        bf[0] = bf16_trunc(mx_qd2(wa0[0], s2, s4, s6, m05, m1, m2));
        bf[1] = bf16_trunc(mx_qd2(wa0[1], s2, s4, s6, m05, m1, m2));
        bf[2] = bf16_trunc(mx_qd2(wa0[2], s2, s4, s6, m05, m1, m2));
        bf[3] = bf16_trunc(mx_qd2(wa0[3], s2, s4, s6, m05, m1, m2));
        bf[4] = bf16_trunc(mx_qd2(wa1[0], s2, s4, s6, m05, m1, m2));
        bf[5] = bf16_trunc(mx_qd2(wa1[1], s2, s4, s6, m05, m1, m2));
        bf[6] = bf16_trunc(mx_qd2(wa1[2], s2, s4, s6, m05, m1, m2));
        bf[7] = bf16_trunc(mx_qd2(wa1[3], s2, s4, s6, m05, m1, m2));

        acc0 = __builtin_amdgcn_mfma_f32_16x16x32_bf16(aa0, bf, acc0, 0, 0, 0);
        acc1 = __builtin_amdgcn_mfma_f32_16x16x32_bf16(aa1, bf, acc1, 0, 0, 0);
        acc2 = __builtin_amdgcn_mfma_f32_16x16x32_bf16(aa2, bf, acc2, 0, 0, 0);
        acc3 = __builtin_amdgcn_mfma_f32_16x16x32_bf16(aa3, bf, acc3, 0, 0, 0);

        // consts for the NEXT tile; shfl latency overlaps the MFMAs just issued
        float amn = blk_absmax8(wb0, wb1);
        amn = fmaxf(amn, __shfl_xor(amn, 16));
        amn = fmaxf(amn, __shfl_xor(amn, 32));
        mx_consts(amn, s2, s4, s6, m05, m1, m2);

        wa0 = wb0; wa1 = wb1;
        wb0 = wc0; wb1 = wc1;
        aa0 = ab0; aa1 = ab1; aa2 = ab2; aa3 = ab3;
    }

    // C/D map: col(n)=lane&15, row(m)=quad*4+reg (verified: absmax 0)
    float* pp = partial + (size_t)split * (TM * DOUT) + (size_t)(nch * 16 + nlo);
    const int mrow = kq * 4;
    #pragma unroll
    for (int r = 0; r < 4; ++r) {
        pp[(size_t)(mrow + r) * DOUT]      = acc0[r];
        pp[(size_t)(16 + mrow + r) * DOUT] = acc1[r];
        pp[(size_t)(32 + mrow + r) * DOUT] = acc2[r];
        pp[(size_t)(48 + mrow + r) * DOUT] = acc3[r];
    }
}

// ---------------- kernel 3: reduce K-splits + quantized bias ----------------
__global__ __launch_bounds__(256) void reduce_bias_kernel(const float* __restrict__ partial,
                                                          const float* __restrict__ bias,
                                                          float* __restrict__ out) {
    int gid = blockIdx.x * 256 + threadIdx.x;       // 704512 threads
    float s = 0.f;
    #pragma unroll
    for (int i = 0; i < KSPLIT; ++i)
        s += partial[(size_t)i * (TM * DOUT) + gid];
    int n = gid % DOUT;
    float v = bias[n];
    float am = fabsf(v);
    am = fmaxf(am, __shfl_xor(am, 1));
    am = fmaxf(am, __shfl_xor(am, 2));
    am = fmaxf(am, __shfl_xor(am, 4));
    am = fmaxf(am, __shfl_xor(am, 8));
    am = fmaxf(am, __shfl_xor(am, 16));
    float s2, s4, s6, m05, m1, m2;
    mx_consts(am, s2, s4, s6, m05, m1, m2);
    out[gid] = s + mx_qd2(v, s2, s4, s6, m05, m1, m2);
}

extern "C" void kernel_launch(void* const* d_in, const int* in_sizes, int n_in,
                              void* d_out, int out_size, void* d_ws, size_t ws_size,
                              hipStream_t stream) {
    const float* x    = (const float*)d_in[0];   // [64, 4096]
    const float* wgt  = (const float*)d_in[1];   // [11008, 4096]
    const float* bias = (const float*)d_in[2];   // [11008]
    float* out = (float*)d_out;                  // [64, 11008]

    unsigned short* x_dq    = (unsigned short*)d_ws;                 // 512 KB
    float*          partial = (float*)((char*)d_ws + 512 * 1024);    // 11.25 MB

    quant_x_kernel<<<256, 256, 0, stream>>>(x, x_dq);
    gemm_kernel<<<NCHUNKS * KSPLIT / 4, 256, 0, stream>>>(x_dq, wgt, partial);
    reduce_bias_kernel<<<TM * DOUT / 256, 256, 0, stream>>>(partial, bias, out);
}

// Round 6
// 276.472 us; speedup vs baseline: 1.0459x; 1.0452x over previous
//
#include <hip/hip_runtime.h>
#include <hip/hip_bf16.h>

#define DIN    4096
#define DOUT   11008
#define TM     64
#define KSPLIT 8
#define KCHUNK (DIN / KSPLIT)     // 512
#define TPS    (KCHUNK / 32)      // 16 K-tiles per split
#define NCHUNKS (DOUT / 16)       // 688

typedef __attribute__((ext_vector_type(8))) short  bf16x8;
typedef __attribute__((ext_vector_type(4))) float  f32x4;

// Per-block constants for scaled-domain E2M1 quant-dequant.
// thresholds s2=2*scale, s4=4*scale, s6=6*scale (saturation) and magic
// rounders m05=2^22*scale, m1=2^23*scale, m2=2^24*scale. All exact pow2*scale.
__device__ inline void mx_consts(float amax, float& s2, float& s4, float& s6,
                                 float& m05, float& m1, float& m2) {
    float safe = amax > 0.0f ? amax : 1.0f;
    int e  = (int)((__float_as_uint(safe) >> 23) & 255) - 127;  // floor(log2), normals
    int se = e - 2;
    if (se < -127) se = -127;            // E8M0_MIN clip (matches jnp clip)
    float scale = ldexpf(1.0f, se);
    s2  = scale + scale;
    s4  = s2 + s2;
    s6  = s4 + s2;
    m05 = ldexpf(scale, 22);             // ulp(m05) = scale/2  -> 0.5-step grid
    m1  = m05 + m05;                     // ulp = scale         -> 1-step grid
    m2  = m1 + m1;                       // ulp = 2*scale       -> 2-step grid
}

// E2M1 quant-dequant, scaled domain: clamp to 6*scale, pick step grid by
// magnitude, round-half-even via (a+mg)-mg (== jnp.round semantics), resign.
__device__ inline float mx_qd2(float v, float s2, float s4, float s6,
                               float m05, float m1, float m2) {
    float a  = fminf(fabsf(v), s6);
    float mg = (a < s2) ? m05 : ((a < s4) ? m1 : m2);
    float q  = (a + mg) - mg;            // exact RNE to the grid (no fast-math)
    return copysignf(q, v);
}

__device__ inline short bf16_trunc(float f) {
    // dequantized values have <=2 mantissa bits -> truncation exact
    return (short)(__float_as_uint(f) >> 16);
}

__device__ inline float blk_absmax8(const f32x4& a, const f32x4& b) {
    return fmaxf(fmaxf(fmaxf(fabsf(a[0]), fabsf(a[1])), fmaxf(fabsf(a[2]), fabsf(a[3]))),
                 fmaxf(fmaxf(fabsf(b[0]), fabsf(b[1])), fmaxf(fabsf(b[2]), fabsf(b[3]))));
}

// ---------------- kernel 1: quantize x -> bf16 tiles in ws (exact) ----------------
// Output layout: x_t[kb][row][j], kb=k/32 (128 tiles), row 0..63, j=k%32.
// Each 4 KB tile is exactly what one gemm K-step consumes, contiguously.
__global__ __launch_bounds__(256) void quant_x_kernel(const float* __restrict__ x,
                                                      unsigned short* __restrict__ x_t) {
    int gid = blockIdx.x * 256 + threadIdx.x;       // 65536 threads x 4 elems
    const float4 v = *(const float4*)(x + (size_t)gid * 4);
    float am = fmaxf(fmaxf(fabsf(v.x), fabsf(v.y)), fmaxf(fabsf(v.z), fabsf(v.w)));
    am = fmaxf(am, __shfl_xor(am, 1));
    am = fmaxf(am, __shfl_xor(am, 2));
    am = fmaxf(am, __shfl_xor(am, 4));              // 8-lane group = one 32-block
    float s2, s4, s6, m05, m1, m2;
    mx_consts(am, s2, s4, s6, m05, m1, m2);
    ushort4 q;
    q.x = (unsigned short)bf16_trunc(mx_qd2(v.x, s2, s4, s6, m05, m1, m2));
    q.y = (unsigned short)bf16_trunc(mx_qd2(v.y, s2, s4, s6, m05, m1, m2));
    q.z = (unsigned short)bf16_trunc(mx_qd2(v.z, s2, s4, s6, m05, m1, m2));
    q.w = (unsigned short)bf16_trunc(mx_qd2(v.w, s2, s4, s6, m05, m1, m2));
    int c4 = gid * 4;
    int r  = c4 >> 12;            // row 0..63
    int c  = c4 & 4095;           // col in K
    int kb = c >> 5;
    int j  = c & 31;
    *(ushort4*)(x_t + (size_t)kb * (64 * 32) + r * 32 + j) = q;
}

// ---------------- kernel 2: barrier-free fused W-quant GEMM ----------------
// One wave owns 16 N-rows and one K-chunk of 512 (16 tiles of 32).
// Per-wave K-phase rotation decorrelates the 16KB-stride W accesses across
// L2/HBM channels (all waves previously started at the same k phase and every
// W load's 16 rows alias mod 4KB -> channel camping, observed 1.7 TB/s).
// B fragment straight from global; A fragment from the contiguous x_t tiles.
// Pipeline: W depth 2, A depth 1, consts depth 1 (shfl overlaps MFMAs).
__global__ __launch_bounds__(256) void gemm_kernel(const unsigned short* __restrict__ x_t,
                                                   const float* __restrict__ wgt,
                                                   float* __restrict__ partial) {
    const int lane  = threadIdx.x & 63;
    const int wid   = threadIdx.x >> 6;
    const int w     = blockIdx.x * 4 + wid;         // 0..5503
    const int nch   = w % NCHUNKS;
    const int split = w / NCHUNKS;
    const int phase = (w * 11) & (TPS - 1);         // per-wave K start offset
    const int nlo   = lane & 15;
    const int kq    = lane >> 4;                    // quad 0..3

    const float*          wp = wgt + (size_t)(nch * 16 + nlo) * DIN + kq * 8;
    const unsigned short* xt = x_t + nlo * 32 + kq * 8;

    f32x4 acc0 = {0.f,0.f,0.f,0.f};
    f32x4 acc1 = {0.f,0.f,0.f,0.f};
    f32x4 acc2 = {0.f,0.f,0.f,0.f};
    f32x4 acc3 = {0.f,0.f,0.f,0.f};

    auto kb_of = [&](int t) { return split * TPS + ((t + phase) & (TPS - 1)); };

    // prologue: W tiles t=0 (consts ready) and t=1 in flight; A frags for t=0
    const int kb0 = kb_of(0), kb1 = kb_of(1);
    f32x4 wa0 = *(const f32x4*)(wp + kb0 * 32);
    f32x4 wa1 = *(const f32x4*)(wp + kb0 * 32 + 4);
    f32x4 wb0 = *(const f32x4*)(wp + kb1 * 32);
    f32x4 wb1 = *(const f32x4*)(wp + kb1 * 32 + 4);
    const unsigned short* xt0 = xt + (size_t)kb0 * 2048;
    bf16x8 aa0 = *(const bf16x8*)(xt0);
    bf16x8 aa1 = *(const bf16x8*)(xt0 + 512);
    bf16x8 aa2 = *(const bf16x8*)(xt0 + 1024);
    bf16x8 aa3 = *(const bf16x8*)(xt0 + 1536);
    float s2, s4, s6, m05, m1, m2;
    {
        float am = blk_absmax8(wa0, wa1);
        am = fmaxf(am, __shfl_xor(am, 16));
        am = fmaxf(am, __shfl_xor(am, 32));
        mx_consts(am, s2, s4, s6, m05, m1, m2);
    }

    #pragma unroll 4
    for (int t = 0; t < TPS; ++t) {
        // prefetch W(t+2) and A(t+1); wrap duplicates at the tail are dead loads
        const int kbw = kb_of(t + 2 >= TPS ? t + 2 - TPS : t + 2);
        const int kba = kb_of(t + 1 >= TPS ? t + 1 - TPS : t + 1);
        f32x4 wc0 = *(const f32x4*)(wp + kbw * 32);
        f32x4 wc1 = *(const f32x4*)(wp + kbw * 32 + 4);
        const unsigned short* xta = xt + (size_t)kba * 2048;
        bf16x8 ab0 = *(const bf16x8*)(xta);
        bf16x8 ab1 = *(const bf16x8*)(xta + 512);
        bf16x8 ab2 = *(const bf16x8*)(xta + 1024);
        bf16x8 ab3 = *(const bf16x8*)(xta + 1536);

        // quantize current W tile with the pre-computed consts
        bf16x8 bf;
        bf[0] = bf16_trunc(mx_qd2(wa0[0], s2, s4, s6, m05, m1, m2));
        bf[1] = bf16_trunc(mx_qd2(wa0[1], s2, s4, s6, m05, m1, m2));
        bf[2] = bf16_trunc(mx_qd2(wa0[2], s2, s4, s6, m05, m1, m2));
        bf[3] = bf16_trunc(mx_qd2(wa0[3], s2, s4, s6, m05, m1, m2));
        bf[4] = bf16_trunc(mx_qd2(wa1[0], s2, s4, s6, m05, m1, m2));
        bf[5] = bf16_trunc(mx_qd2(wa1[1], s2, s4, s6, m05, m1, m2));
        bf[6] = bf16_trunc(mx_qd2(wa1[2], s2, s4, s6, m05, m1, m2));
        bf[7] = bf16_trunc(mx_qd2(wa1[3], s2, s4, s6, m05, m1, m2));

        acc0 = __builtin_amdgcn_mfma_f32_16x16x32_bf16(aa0, bf, acc0, 0, 0, 0);
        acc1 = __builtin_amdgcn_mfma_f32_16x16x32_bf16(aa1, bf, acc1, 0, 0, 0);
        acc2 = __builtin_amdgcn_mfma_f32_16x16x32_bf16(aa2, bf, acc2, 0, 0, 0);
        acc3 = __builtin_amdgcn_mfma_f32_16x16x32_bf16(aa3, bf, acc3, 0, 0, 0);

        // consts for the NEXT tile; shfl latency overlaps the MFMAs just issued
        float amn = blk_absmax8(wb0, wb1);
        amn = fmaxf(amn, __shfl_xor(amn, 16));
        amn = fmaxf(amn, __shfl_xor(amn, 32));
        mx_consts(amn, s2, s4, s6, m05, m1, m2);

        wa0 = wb0; wa1 = wb1;
        wb0 = wc0; wb1 = wc1;
        aa0 = ab0; aa1 = ab1; aa2 = ab2; aa3 = ab3;
    }

    // C/D map: col(n)=lane&15, row(m)=quad*4+reg (verified: absmax 0)
    float* pp = partial + (size_t)split * (TM * DOUT) + (size_t)(nch * 16 + nlo);
    const int mrow = kq * 4;
    #pragma unroll
    for (int r = 0; r < 4; ++r) {
        pp[(size_t)(mrow + r) * DOUT]      = acc0[r];
        pp[(size_t)(16 + mrow + r) * DOUT] = acc1[r];
        pp[(size_t)(32 + mrow + r) * DOUT] = acc2[r];
        pp[(size_t)(48 + mrow + r) * DOUT] = acc3[r];
    }
}

// ---------------- kernel 3: reduce K-splits + quantized bias ----------------
__global__ __launch_bounds__(256) void reduce_bias_kernel(const float* __restrict__ partial,
                                                          const float* __restrict__ bias,
                                                          float* __restrict__ out) {
    int gid = blockIdx.x * 256 + threadIdx.x;       // 704512 threads
    float s = 0.f;
    #pragma unroll
    for (int i = 0; i < KSPLIT; ++i)
        s += partial[(size_t)i * (TM * DOUT) + gid];
    int n = gid % DOUT;
    float v = bias[n];
    float am = fabsf(v);
    am = fmaxf(am, __shfl_xor(am, 1));
    am = fmaxf(am, __shfl_xor(am, 2));
    am = fmaxf(am, __shfl_xor(am, 4));
    am = fmaxf(am, __shfl_xor(am, 8));
    am = fmaxf(am, __shfl_xor(am, 16));
    float s2, s4, s6, m05, m1, m2;
    mx_consts(am, s2, s4, s6, m05, m1, m2);
    out[gid] = s + mx_qd2(v, s2, s4, s6, m05, m1, m2);
}

extern "C" void kernel_launch(void* const* d_in, const int* in_sizes, int n_in,
                              void* d_out, int out_size, void* d_ws, size_t ws_size,
                              hipStream_t stream) {
    const float* x    = (const float*)d_in[0];   // [64, 4096]
    const float* wgt  = (const float*)d_in[1];   // [11008, 4096]
    const float* bias = (const float*)d_in[2];   // [11008]
    float* out = (float*)d_out;                  // [64, 11008]

    unsigned short* x_t     = (unsigned short*)d_ws;                 // 512 KB
    float*          partial = (float*)((char*)d_ws + 512 * 1024);    // 22.5 MB

    quant_x_kernel<<<256, 256, 0, stream>>>(x, x_t);
    gemm_kernel<<<NCHUNKS * KSPLIT / 4, 256, 0, stream>>>(x_t, wgt, partial);
    reduce_bias_kernel<<<TM * DOUT / 256, 256, 0, stream>>>(partial, bias, out);
}